// Round 20
// baseline (137.893 us; speedup 1.0000x reference)
//
#include <hip/hip_runtime.h>

#define DIMK 512
#define NHEADS 8
#define DH 64
#define NBATCH 16
#define QLEN 512
#define KVLEN 1024
#define NQ (NBATCH*QLEN)     /* 8192  */
#define NKV (NBATCH*KVLEN)   /* 16384 */

typedef __attribute__((ext_vector_type(8))) short bf16x8;
typedef __attribute__((ext_vector_type(4))) float f32x4;
typedef __attribute__((ext_vector_type(8))) unsigned short us8;

#define QSCL 0.1803368801111204f   /* 0.125 * log2(e) : folded into q */

__device__ __forceinline__ float bf2f(unsigned short u) {
    return __uint_as_float(((unsigned)u) << 16);
}
__device__ __forceinline__ unsigned short f2bf(float f) {
    unsigned u = __float_as_uint(f);
    return (unsigned short)((u + 0x7fffu + ((u >> 16) & 1u)) >> 16);
}
__device__ __forceinline__ unsigned cvtpk(float a, float b) {
    unsigned r;
    asm("v_cvt_pk_bf16_f32 %0, %1, %2" : "=v"(r) : "v"(a), "v"(b));
    return r;
}
__device__ __forceinline__ void gl2lds16(const void* g, const void* lds) {
    __builtin_amdgcn_global_load_lds(
        (const __attribute__((address_space(1))) unsigned int*)g,
        (__attribute__((address_space(3))) unsigned int*)lds, 16, 0, 0);
}

// ---------------------------------------------------------------------------
// Fused prep (r17 verbatim): sincos tables, LN+cast, weight transposes.
// ---------------------------------------------------------------------------
__global__ __launch_bounds__(256) void prep_kernel(
    const float* __restrict__ fq, const float* __restrict__ fkv,
    float2* __restrict__ fqt,
    const float* __restrict__ xa, const float* __restrict__ xb,
    const float* __restrict__ ga, const float* __restrict__ ba,
    const float* __restrict__ gb, const float* __restrict__ bb,
    unsigned short* __restrict__ xout,
    const float* __restrict__ Wq, unsigned short* __restrict__ WqT,
    const float* __restrict__ Wkv, unsigned short* __restrict__ WkvT,
    const float* __restrict__ Wout, unsigned short* __restrict__ WoutTh,
    unsigned short* __restrict__ WoutTl)
{
    const int bid = blockIdx.x;
    const int tid = threadIdx.x;
    if (bid < 6144) {
        int i = bid * 256 + tid;
        const int na = NQ * DH;
        float f = (i < na) ? fq[i] : fkv[i - na];
        float sn, cs;
        sincosf(f, &sn, &cs);
        fqt[i] = make_float2(cs, sn);
    } else if (bid < 12288) {
        int row  = (bid - 6144) * 4 + (tid >> 6);
        int lane = tid & 63;
        bool isa = row < NQ;
        const float* x  = isa ? xa + (size_t)row * DIMK : xb + (size_t)(row - NQ) * DIMK;
        const float* g  = isa ? ga : gb;
        const float* bt = isa ? ba : bb;
        const float4* xr = reinterpret_cast<const float4*>(x);
        float4 v0 = xr[lane * 2];
        float4 v1 = xr[lane * 2 + 1];
        float s  = v0.x + v0.y + v0.z + v0.w + v1.x + v1.y + v1.z + v1.w;
        float sq = v0.x*v0.x + v0.y*v0.y + v0.z*v0.z + v0.w*v0.w
                 + v1.x*v1.x + v1.y*v1.y + v1.z*v1.z + v1.w*v1.w;
        #pragma unroll
        for (int off = 32; off; off >>= 1) {
            s  += __shfl_xor(s, off);
            sq += __shfl_xor(sq, off);
        }
        float mu   = s * (1.0f / DIMK);
        float rstd = rsqrtf(sq * (1.0f / DIMK) - mu * mu + 1e-5f);
        const float4* g4 = reinterpret_cast<const float4*>(g + lane * 8);
        const float4* b4 = reinterpret_cast<const float4*>(bt + lane * 8);
        float4 g0 = g4[0], g1 = g4[1], b0 = b4[0], b1 = b4[1];
        us8 o;
        o[0] = f2bf((v0.x - mu) * rstd * g0.x + b0.x);
        o[1] = f2bf((v0.y - mu) * rstd * g0.y + b0.y);
        o[2] = f2bf((v0.z - mu) * rstd * g0.z + b0.z);
        o[3] = f2bf((v0.w - mu) * rstd * g0.w + b0.w);
        o[4] = f2bf((v1.x - mu) * rstd * g1.x + b1.x);
        o[5] = f2bf((v1.y - mu) * rstd * g1.y + b1.y);
        o[6] = f2bf((v1.z - mu) * rstd * g1.z + b1.z);
        o[7] = f2bf((v1.w - mu) * rstd * g1.w + b1.w);
        *reinterpret_cast<us8*>(xout + (size_t)row * DIMK + lane * 8) = o;
    } else if (bid < 13312) {
        int idx = (bid - 12288) * 256 + tid;
        int n = idx >> 9, k = idx & 511;
        WqT[idx] = f2bf(Wq[(size_t)k * 512 + n]);
    } else if (bid < 15360) {
        int idx = (bid - 13312) * 256 + tid;
        int n = idx >> 9, k = idx & 511;
        WkvT[idx] = f2bf(Wkv[(size_t)k * 1024 + n]);
    } else {
        int idx = (bid - 15360) * 256 + tid;
        int n = idx >> 9, k = idx & 511;
        float v = Wout[(size_t)k * 512 + n];
        unsigned short h = f2bf(v);
        WoutTh[idx] = h;
        WoutTl[idx] = f2bf(v - bf2f(h));
    }
}

// ---------------------------------------------------------------------------
// Fused q+kv projection GEMM, BK=64 variant of the r15 structure: same 128x128
// tile, 4 waves, same 2-phase stage->barrier->MFMA->barrier skeleton, but each
// K-step covers 64 of K (two 32-wide MFMA sub-phases) -> 8 barrier pairs
// instead of 16, 2x staging bytes and 2x MFMA per barrier. LDS 64KB (2 blk/CU,
// same occupancy as before). acc/thread unchanged (64 VGPR).
// grid 1280: tiles 0..255 q-proj (*QSCL), 256..1279 kv-proj (k / v->vT).
// ---------------------------------------------------------------------------
__global__ __launch_bounds__(256, 2) void mmqkv_kernel(
    const unsigned short* __restrict__ xq, const unsigned short* __restrict__ xc,
    const unsigned short* __restrict__ WqT, const unsigned short* __restrict__ WkvT,
    unsigned short* __restrict__ qbout, unsigned short* __restrict__ kbout,
    unsigned short* __restrict__ vTout,
    const float2* __restrict__ fqt, const float2* __restrict__ fkvt)
{
    __shared__ __align__(16) unsigned short AsH[2][128 * 64];   // 2 x 16 KB
    __shared__ __align__(16) unsigned short BsH[2][128 * 64];   // 2 x 16 KB

    const int t = threadIdx.x;
    const int lane = t & 63, w = t >> 6;
    const int l15 = lane & 15, l4 = lane >> 4;
    const int wr = w >> 1, wc = w & 1;

    const int nwg  = gridDim.x;                 // 1280
    const int tile = (blockIdx.x & 7) * (nwg >> 3) + (blockIdx.x >> 3);
    const bool isq = tile < 256;
    const int tl   = isq ? tile : tile - 256;
    const int NCT  = isq ? 4 : 8;
    const unsigned short* A = isq ? xq : xc;
    const unsigned short* B = isq ? WqT : WkvT;
    const float2* fct = isq ? fqt : fkvt;
    const int row0 = (tl / NCT) * 128;
    const int col0 = (tl % NCT) * 128;

    // stage: 8 calls/thread; each wave call covers 8 rows x 64 cols (1 KB)
    const int stRow = lane >> 3;          // 0..7 within 8-row group
    const int stK   = (lane & 7) * 8;     // 16B chunk within 64-elem row

    auto stage = [&](int buf, int k0) {
        #pragma unroll
        for (int j = 0; j < 8; ++j) {
            int id  = w * 8 + j;          // 0..31
            bool isA = id < 16;
            int sub = isA ? id : id - 16; // 0..15 (8-row group)
            int row = sub * 8 + stRow;
            const unsigned short* gsrc = isA
                ? A + (size_t)(row0 + row) * 512
                : B + (size_t)(col0 + row) * 512;
            unsigned short* ldst = isA ? &AsH[buf][0] : &BsH[buf][0];
            gl2lds16(gsrc + k0 + stK, ldst + sub * 512);
        }
    };

    f32x4 acc[4][4];
    #pragma unroll
    for (int m = 0; m < 4; ++m)
        #pragma unroll
        for (int n = 0; n < 4; ++n)
            acc[m][n] = (f32x4){0.f, 0.f, 0.f, 0.f};

    stage(0, 0);
    __syncthreads();

    for (int ks = 0; ks < 8; ++ks) {
        const int cur = ks & 1;
        if (ks < 7) stage(cur ^ 1, (ks + 1) * 64);

        #pragma unroll
        for (int kk = 0; kk < 2; ++kk) {
            bf16x8 fah[4], fbh[4];
            #pragma unroll
            for (int m = 0; m < 4; ++m)
                fah[m] = *reinterpret_cast<const bf16x8*>(
                    &AsH[cur][(wr*64 + m*16 + l15) * 64 + kk*32 + l4*8]);
            #pragma unroll
            for (int n = 0; n < 4; ++n)
                fbh[n] = *reinterpret_cast<const bf16x8*>(
                    &BsH[cur][(wc*64 + n*16 + l15) * 64 + kk*32 + l4*8]);
            #pragma unroll
            for (int m = 0; m < 4; ++m)
                #pragma unroll
                for (int n = 0; n < 4; ++n)
                    acc[m][n] = __builtin_amdgcn_mfma_f32_16x16x32_bf16(fah[m], fbh[n], acc[m][n], 0, 0, 0);
        }
        __syncthreads();
    }

    // wave-private 8KB pool (4096 shorts) carved from dead AsH (32KB total)
    unsigned short* pool = &AsH[0][0] + w * 4096;

    if (!isq && col0 >= 512) {
        const int vb    = row0 >> 10;
        const int kbase = (row0 & 1023) + wr * 64;
        const int vh    = ((col0 - 512) >> 6) + wc;
        #pragma unroll
        for (int m = 0; m < 4; ++m)
            #pragma unroll
            for (int n = 0; n < 4; ++n)
                #pragma unroll
                for (int j = 0; j < 4; ++j) {
                    float v = acc[m][n][j];
                    int gr = row0 + wr*64 + m*16 + l4*4 + j;
                    int d  = n*16 + l15;
                    float pv = __shfl_xor(v, 1);
                    float2 cn = fct[(size_t)gr * DH + d];
                    float nv = (lane & 1) ? fmaf(pv, cn.y, v * cn.x)
                                          : fmaf(-pv, cn.y, v * cn.x);
                    int kloc = m*16 + l4*4 + j;
                    int ch   = (kloc >> 3) ^ (d & 7);
                    pool[d*64 + ch*8 + (kloc & 7)] = f2bf(nv);
                }
        #pragma unroll
        for (int i = 0; i < 8; ++i) {
            int c   = i * 64 + lane;
            int dd  = c >> 3, chq = c & 7;
            int sw  = chq ^ (dd & 7);
            us8 vv = *reinterpret_cast<const us8*>(&pool[dd*64 + sw*8]);
            *reinterpret_cast<us8*>(
                &vTout[(size_t)((vb * 8 + vh) * 64 + dd) * 1024 + kbase + chq * 8]) = vv;
        }
    } else {
        unsigned short* Cout = isq ? qbout : kbout;
        #pragma unroll
        for (int m = 0; m < 4; ++m)
            #pragma unroll
            for (int n = 0; n < 4; ++n)
                #pragma unroll
                for (int j = 0; j < 4; ++j) {
                    float v = acc[m][n][j];
                    int gr = row0 + wr*64 + m*16 + l4*4 + j;
                    int d  = n*16 + l15;
                    float pv = __shfl_xor(v, 1);
                    float2 cn = fct[(size_t)gr * DH + d];
                    float nv = (lane & 1) ? fmaf(pv, cn.y, v * cn.x)
                                          : fmaf(-pv, cn.y, v * cn.x);
                    if (isq) nv *= QSCL;
                    int row = m*16 + l4*4 + j;
                    int col = n*16 + l15;
                    int ch  = (col >> 3) ^ (row & 7);
                    pool[row*64 + ch*8 + (col & 7)] = f2bf(nv);
                }
        #pragma unroll
        for (int i = 0; i < 8; ++i) {
            int c  = i * 64 + lane;
            int rl = c >> 3, ch = c & 7;
            int sw = ch ^ (rl & 7);
            us8 vv = *reinterpret_cast<const us8*>(&pool[rl*64 + sw*8]);
            int gr = row0 + wr*64 + rl;
            int gc = col0 + wc*64 + ch*8;
            *reinterpret_cast<us8*>(&Cout[(size_t)gr * 512 + gc]) = vv;
        }
    }
}

// ---------------------------------------------------------------------------
// Output GEMM (split bf16, 3 MFMA) — r17 verbatim.
// ---------------------------------------------------------------------------
__global__ __launch_bounds__(256, 2) void mm2_kernel(
    const unsigned short* __restrict__ Ah, const unsigned short* __restrict__ Al,
    const unsigned short* __restrict__ Bh, const unsigned short* __restrict__ Bl,
    float* __restrict__ Cout, const float* __restrict__ bias)
{
    __shared__ __align__(16) unsigned short AsH[2][128 * 32];
    __shared__ __align__(16) unsigned short BsH[2][128 * 32];
    __shared__ __align__(16) unsigned short AsL[2][128 * 32];
    __shared__ __align__(16) unsigned short BsL[2][128 * 32];

    const int t = threadIdx.x;
    const int lane = t & 63, w = t >> 6;
    const int l15 = lane & 15, l4 = lane >> 4;
    const int wr = w >> 1, wc = w & 1;

    const int nwg  = gridDim.x;
    const int tile = (blockIdx.x & 7) * (nwg >> 3) + (blockIdx.x >> 3);
    const int row0 = (tile >> 2) * 128;
    const int col0 = (tile & 3) * 128;

    const int stRow = lane >> 2;
    const int stK   = (lane & 3) * 8;

    auto stage = [&](int buf, int k0) {
        #pragma unroll
        for (int j = 0; j < 8; ++j) {
            int id  = w * 8 + j;
            int mat = id >> 3;
            int sub = id & 7;
            int row = sub * 16 + stRow;
            const unsigned short* gsrc =
                (mat == 0) ? Ah + (size_t)(row0 + row) * 512 :
                (mat == 1) ? Bh + (size_t)(col0 + row) * 512 :
                (mat == 2) ? Al + (size_t)(row0 + row) * 512 :
                             Bl + (size_t)(col0 + row) * 512;
            unsigned short* ldst =
                (mat == 0) ? &AsH[buf][0] :
                (mat == 1) ? &BsH[buf][0] :
                (mat == 2) ? &AsL[buf][0] :
                             &BsL[buf][0];
            gl2lds16(gsrc + k0 + stK, ldst + sub * 512);
        }
    };

    f32x4 acc[4][4];
    #pragma unroll
    for (int m = 0; m < 4; ++m)
        #pragma unroll
        for (int n = 0; n < 4; ++n)
            acc[m][n] = (f32x4){0.f, 0.f, 0.f, 0.f};

    stage(0, 0);
    __syncthreads();

    for (int ks = 0; ks < 16; ++ks) {
        const int cur = ks & 1;
        if (ks < 15) stage(cur ^ 1, (ks + 1) * 32);

        bf16x8 fah[4], fbh[4], fal[4], fbl[4];
        #pragma unroll
        for (int m = 0; m < 4; ++m) {
            fah[m] = *reinterpret_cast<const bf16x8*>(&AsH[cur][(wr*64 + m*16 + l15) * 32 + l4*8]);
            fal[m] = *reinterpret_cast<const bf16x8*>(&AsL[cur][(wr*64 + m*16 + l15) * 32 + l4*8]);
        }
        #pragma unroll
        for (int n = 0; n < 4; ++n) {
            fbh[n] = *reinterpret_cast<const bf16x8*>(&BsH[cur][(wc*64 + n*16 + l15) * 32 + l4*8]);
            fbl[n] = *reinterpret_cast<const bf16x8*>(&BsL[cur][(wc*64 + n*16 + l15) * 32 + l4*8]);
        }
        #pragma unroll
        for (int m = 0; m < 4; ++m)
            #pragma unroll
            for (int n = 0; n < 4; ++n) {
                acc[m][n] = __builtin_amdgcn_mfma_f32_16x16x32_bf16(fah[m], fbh[n], acc[m][n], 0, 0, 0);
                acc[m][n] = __builtin_amdgcn_mfma_f32_16x16x32_bf16(fah[m], fbl[n], acc[m][n], 0, 0, 0);
                acc[m][n] = __builtin_amdgcn_mfma_f32_16x16x32_bf16(fal[m], fbh[n], acc[m][n], 0, 0, 0);
            }
        __syncthreads();
    }

    #pragma unroll
    for (int m = 0; m < 4; ++m)
        #pragma unroll
        for (int n = 0; n < 4; ++n)
            #pragma unroll
            for (int j = 0; j < 4; ++j) {
                int gr = row0 + wr*64 + m*16 + l4*4 + j;
                int gc = col0 + wc*64 + n*16 + l15;
                Cout[(size_t)gr * 512 + gc] = acc[m][n][j] + bias[gc];
            }
}

// ---------------------------------------------------------------------------
// MFMA flash attention — r17 verbatim (passing): r12 sync structure +
// q-multi x2, disjoint P regions, no setprio.
// ---------------------------------------------------------------------------
__global__ __launch_bounds__(256, 2) void attn_kernel(
    const unsigned short* __restrict__ kb, const unsigned short* __restrict__ qb,
    const unsigned short* __restrict__ vT, const float2* __restrict__ fqt,
    unsigned short* __restrict__ aobH, unsigned short* __restrict__ aobL)
{
    __shared__ __align__(16) unsigned short Vs[4][4096];   // 4-buffer V ring
    __shared__ __align__(16) unsigned short Ps[4][2048];   // [wave][set*1024+idx]

    const int bid  = blockIdx.x;
    const int tile = (bid & 7) * 64 + (bid >> 3);   // nwg=512, bijective
    const int qs = tile & 3, h = (tile >> 2) & 7, b = tile >> 5;
    const int t = threadIdx.x, lane = t & 63, w = t >> 6;
    const int l15 = lane & 15, l4 = lane >> 4;
    const int bh = b * 8 + h;

    const int q_row0 = b * QLEN + qs * 128 + w * 16;   // set0; set1 = +64
    const size_t kvr0 = (size_t)b * KVLEN;

    constexpr float RTHR = 11.5415585f;   // 8 * log2e (exp2 domain)

    bf16x8 qf0 = *reinterpret_cast<const bf16x8*>(
        &qb[(size_t)(q_row0 + l15) * 512 + h * 64 + l4 * 8]);
    bf16x8 qf1 = *reinterpret_cast<const bf16x8*>(
        &qb[(size_t)(q_row0 + l15) * 512 + h * 64 + 32 + l4 * 8]);
    bf16x8 qg0 = *reinterpret_cast<const bf16x8*>(
        &qb[(size_t)(q_row0 + 64 + l15) * 512 + h * 64 + l4 * 8]);
    bf16x8 qg1 = *reinterpret_cast<const bf16x8*>(
        &qb[(size_t)(q_row0 + 64 + l15) * 512 + h * 64 + 32 + l4 * 8]);

    auto stageVT = [&](int buf, int kt) {
        #pragma unroll
        for (int i = 0; i < 2; ++i) {
            const int dbase = (w * 2 + i) * 8;
            const int dlo = lane >> 3;
            const int cb  = lane & 7;
            gl2lds16(&vT[(size_t)(bh * 64 + dbase + dlo) * 1024 + kt * 64
                         + ((cb ^ dlo) * 8)],
                     &Vs[buf][dbase * 64]);
        }
    };

    auto loadK = [&](bf16x8 (&dst)[4][2], int kt) {
        #pragma unroll
        for (int n = 0; n < 4; ++n) {
            const unsigned short* krow =
                &kb[(kvr0 + kt * 64 + n * 16 + l15) * 512 + h * 64];
            dst[n][0] = *reinterpret_cast<const bf16x8*>(&krow[l4 * 8]);
            dst[n][1] = *reinterpret_cast<const bf16x8*>(&krow[32 + l4 * 8]);
        }
    };

    f32x4 o0[4], o1[4];
    #pragma unroll
    for (int dt = 0; dt < 4; ++dt) {
        o0[dt] = (f32x4){0.f, 0.f, 0.f, 0.f};
        o1[dt] = (f32x4){0.f, 0.f, 0.f, 0.f};
    }
    float m0 = -3.0e38f, l0 = 0.f, m1 = -3.0e38f, l1 = 0.f;

    unsigned short* pw0 = &Ps[w][0];
    unsigned short* pw1 = &Ps[w][1024];

    auto iter = [&](int vbuf, bf16x8 (&KC)[4][2]) {
        // ================= set 0 =================
        {
            f32x4 s[4];
            #pragma unroll
            for (int n = 0; n < 4; ++n) {
                f32x4 a = (f32x4){0.f, 0.f, 0.f, 0.f};
                a = __builtin_amdgcn_mfma_f32_16x16x32_bf16(KC[n][0], qf0, a, 0, 0, 0);
                a = __builtin_amdgcn_mfma_f32_16x16x32_bf16(KC[n][1], qf1, a, 0, 0, 0);
                s[n] = a;
            }
            float pmax = -3.0e38f;
            #pragma unroll
            for (int n = 0; n < 4; ++n)
                #pragma unroll
                for (int j = 0; j < 4; ++j)
                    pmax = fmaxf(pmax, s[n][j]);
            pmax = fmaxf(pmax, __shfl_xor(pmax, 16));
            pmax = fmaxf(pmax, __shfl_xor(pmax, 32));
            if (!__all(pmax - m0 <= RTHR)) {
                float mnew = fmaxf(m0, pmax);
                float al = __builtin_amdgcn_exp2f(m0 - mnew);
                l0 *= al;
                float a0 = __shfl(al, l4 * 4 + 0);
                float a1 = __shfl(al, l4 * 4 + 1);
                float a2 = __shfl(al, l4 * 4 + 2);
                float a3 = __shfl(al, l4 * 4 + 3);
                #pragma unroll
                for (int dt = 0; dt < 4; ++dt) {
                    o0[dt][0] *= a0; o0[dt][1] *= a1; o0[dt][2] *= a2; o0[dt][3] *= a3;
                }
                m0 = mnew;
            }
            float rs = 0.f;
            #pragma unroll
            for (int n = 0; n < 4; ++n) {
                float p0 = __builtin_amdgcn_exp2f(s[n][0] - m0);
                float p1 = __builtin_amdgcn_exp2f(s[n][1] - m0);
                float p2 = __builtin_amdgcn_exp2f(s[n][2] - m0);
                float p3 = __builtin_amdgcn_exp2f(s[n][3] - m0);
                rs += (p0 + p1) + (p2 + p3);
                uint2 pk = make_uint2(cvtpk(p0, p1), cvtpk(p2, p3));
                int idx = l15 * 64 + ((n * 16 + l4 * 4) ^ ((l15 & 7) << 3));
                *reinterpret_cast<uint2*>(&pw0[idx]) = pk;
            }
            rs += __shfl_xor(rs, 16);
            rs += __shfl_xor(rs, 32);
            l0 += rs;

            bf16x8 pfh[2];
            #pragma unroll
            for (int c = 0; c < 2; ++c) {
                int idx = l15 * 64 + ((c * 32 + l4 * 8) ^ ((l15 & 7) << 3));
                pfh[c] = *reinterpret_cast<const bf16x8*>(&pw0[idx]);
            }
            #pragma unroll
            for (int dt = 0; dt < 4; ++dt) {
                int d = dt * 16 + l15;
                #pragma unroll
                for (int c = 0; c < 2; ++c) {
                    int vidx = d * 64 + ((c * 32 + l4 * 8) ^ ((d & 7) << 3));
                    bf16x8 vf = *reinterpret_cast<const bf16x8*>(&Vs[vbuf][vidx]);
                    o0[dt] = __builtin_amdgcn_mfma_f32_16x16x32_bf16(pfh[c], vf, o0[dt], 0, 0, 0);
                }
            }
        }
        // ================= set 1 =================
        {
            f32x4 s[4];
            #pragma unroll
            for (int n = 0; n < 4; ++n) {
                f32x4 a = (f32x4){0.f, 0.f, 0.f, 0.f};
                a = __builtin_amdgcn_mfma_f32_16x16x32_bf16(KC[n][0], qg0, a, 0, 0, 0);
                a = __builtin_amdgcn_mfma_f32_16x16x32_bf16(KC[n][1], qg1, a, 0, 0, 0);
                s[n] = a;
            }
            float pmax = -3.0e38f;
            #pragma unroll
            for (int n = 0; n < 4; ++n)
                #pragma unroll
                for (int j = 0; j < 4; ++j)
                    pmax = fmaxf(pmax, s[n][j]);
            pmax = fmaxf(pmax, __shfl_xor(pmax, 16));
            pmax = fmaxf(pmax, __shfl_xor(pmax, 32));
            if (!__all(pmax - m1 <= RTHR)) {
                float mnew = fmaxf(m1, pmax);
                float al = __builtin_amdgcn_exp2f(m1 - mnew);
                l1 *= al;
                float a0 = __shfl(al, l4 * 4 + 0);
                float a1 = __shfl(al, l4 * 4 + 1);
                float a2 = __shfl(al, l4 * 4 + 2);
                float a3 = __shfl(al, l4 * 4 + 3);
                #pragma unroll
                for (int dt = 0; dt < 4; ++dt) {
                    o1[dt][0] *= a0; o1[dt][1] *= a1; o1[dt][2] *= a2; o1[dt][3] *= a3;
                }
                m1 = mnew;
            }
            float rs = 0.f;
            #pragma unroll
            for (int n = 0; n < 4; ++n) {
                float p0 = __builtin_amdgcn_exp2f(s[n][0] - m1);
                float p1 = __builtin_amdgcn_exp2f(s[n][1] - m1);
                float p2 = __builtin_amdgcn_exp2f(s[n][2] - m1);
                float p3 = __builtin_amdgcn_exp2f(s[n][3] - m1);
                rs += (p0 + p1) + (p2 + p3);
                uint2 pk = make_uint2(cvtpk(p0, p1), cvtpk(p2, p3));
                int idx = l15 * 64 + ((n * 16 + l4 * 4) ^ ((l15 & 7) << 3));
                *reinterpret_cast<uint2*>(&pw1[idx]) = pk;
            }
            rs += __shfl_xor(rs, 16);
            rs += __shfl_xor(rs, 32);
            l1 += rs;

            bf16x8 pfh[2];
            #pragma unroll
            for (int c = 0; c < 2; ++c) {
                int idx = l15 * 64 + ((c * 32 + l4 * 8) ^ ((l15 & 7) << 3));
                pfh[c] = *reinterpret_cast<const bf16x8*>(&pw1[idx]);
            }
            #pragma unroll
            for (int dt = 0; dt < 4; ++dt) {
                int d = dt * 16 + l15;
                #pragma unroll
                for (int c = 0; c < 2; ++c) {
                    int vidx = d * 64 + ((c * 32 + l4 * 8) ^ ((d & 7) << 3));
                    bf16x8 vf = *reinterpret_cast<const bf16x8*>(&Vs[vbuf][vidx]);
                    o1[dt] = __builtin_amdgcn_mfma_f32_16x16x32_bf16(pfh[c], vf, o1[dt], 0, 0, 0);
                }
            }
        }
    };

    bf16x8 kA[4][2], kB[4][2];
    stageVT(0, 0);
    stageVT(1, 1);
    loadK(kA, 0);

    for (int kt = 0; kt < 16; kt += 2) {
        __syncthreads();
        if (kt < 14) {
            stageVT((kt + 2) & 3, kt + 2);
            stageVT((kt + 3) & 3, kt + 3);
        }
        loadK(kB, kt + 1);
        iter(kt & 3, kA);
        if (kt < 14) loadK(kA, kt + 2);
        iter((kt + 1) & 3, kB);
    }

    __syncthreads();
    unsigned short* pe = &Vs[w][0];

    {   // ---- set 0 ----
        unsigned short* ps = pe;
        float linv = 1.f / l0;
        #pragma unroll
        for (int r = 0; r < 4; ++r) {
            float lr = __shfl(linv, l4 * 4 + r);
            int gr = q_row0 + l4 * 4 + r;
            #pragma unroll
            for (int dt = 0; dt < 4; ++dt) {
                int d = dt * 16 + l15;
                float val = o0[dt][r] * lr;
                float pv = __shfl_xor(val, 1);
                float2 cn = fqt[(size_t)gr * DH + d];
                float rr = (d & 1) ? (val * cn.x - pv * cn.y) : (val * cn.x + pv * cn.y);
                unsigned short hi = f2bf(rr);
                float lo = rr - bf2f(hi);
                int row = l4 * 4 + r;
                int ch  = (d >> 3) ^ (row & 7);
                ps[row*64 + ch*8 + (d & 7)] = hi;
                ps[1024 + row*64 + ch*8 + (d & 7)] = f2bf(lo);
            }
        }
        #pragma unroll
        for (int i = 0; i < 2; ++i) {
            int c  = i * 64 + lane;
            int rl = c >> 3, ch = c & 7;
            int sw = ch ^ (rl & 7);
            us8 vh = *reinterpret_cast<const us8*>(&ps[rl*64 + sw*8]);
            us8 vl = *reinterpret_cast<const us8*>(&ps[1024 + rl*64 + sw*8]);
            size_t off = (size_t)(q_row0 + rl) * 512 + h * 64 + ch * 8;
            *reinterpret_cast<us8*>(&aobH[off]) = vh;
            *reinterpret_cast<us8*>(&aobL[off]) = vl;
        }
    }
    {   // ---- set 1 ----
        unsigned short* ps = pe + 2048;
        float linv = 1.f / l1;
        #pragma unroll
        for (int r = 0; r < 4; ++r) {
            float lr = __shfl(linv, l4 * 4 + r);
            int gr = q_row0 + 64 + l4 * 4 + r;
            #pragma unroll
            for (int dt = 0; dt < 4; ++dt) {
                int d = dt * 16 + l15;
                float val = o1[dt][r] * lr;
                float pv = __shfl_xor(val, 1);
                float2 cn = fqt[(size_t)gr * DH + d];
                float rr = (d & 1) ? (val * cn.x - pv * cn.y) : (val * cn.x + pv * cn.y);
                unsigned short hi = f2bf(rr);
                float lo = rr - bf2f(hi);
                int row = l4 * 4 + r;
                int ch  = (d >> 3) ^ (row & 7);
                ps[row*64 + ch*8 + (d & 7)] = hi;
                ps[1024 + row*64 + ch*8 + (d & 7)] = f2bf(lo);
            }
        }
        #pragma unroll
        for (int i = 0; i < 2; ++i) {
            int c  = i * 64 + lane;
            int rl = c >> 3, ch = c & 7;
            int sw = ch ^ (rl & 7);
            us8 vh = *reinterpret_cast<const us8*>(&ps[rl*64 + sw*8]);
            us8 vl = *reinterpret_cast<const us8*>(&ps[1024 + rl*64 + sw*8]);
            size_t off = (size_t)(q_row0 + 64 + rl) * 512 + h * 64 + ch * 8;
            *reinterpret_cast<us8*>(&aobH[off]) = vh;
            *reinterpret_cast<us8*>(&aobL[off]) = vl;
        }
    }
}

// ---------------------------------------------------------------------------
extern "C" void kernel_launch(void* const* d_in, const int* in_sizes, int n_in,
                              void* d_out, int out_size, void* d_ws, size_t ws_size,
                              hipStream_t stream) {
    const float* x_query   = (const float*)d_in[0];
    const float* x_context = (const float*)d_in[1];
    const float* fq        = (const float*)d_in[2];
    const float* fkv       = (const float*)d_in[3];
    const float* ln_q_g    = (const float*)d_in[4];
    const float* ln_q_b    = (const float*)d_in[5];
    const float* ln_c_g    = (const float*)d_in[6];
    const float* ln_c_b    = (const float*)d_in[7];
    const float* Wq        = (const float*)d_in[8];
    const float* Wkv       = (const float*)d_in[9];
    const float* Wout      = (const float*)d_in[10];
    const float* bout      = (const float*)d_in[11];
    float* out = (float*)d_out;

    unsigned short* xq     = (unsigned short*)d_ws;             // 8192*512
    unsigned short* xc     = xq + (size_t)NQ * 512;             // 16384*512
    unsigned short* WqT    = xc + (size_t)NKV * 512;            // 512*512
    unsigned short* WkvT   = WqT + 512 * 512;                   // 1024*512
    unsigned short* WoutTh = WkvT + 1024 * 512;                 // 512*512
    unsigned short* WoutTl = WoutTh + 512 * 512;                // 512*512
    unsigned short* qb     = WoutTl + 512 * 512;                // 8192*512
    unsigned short* kb     = qb + (size_t)NQ * 512;             // 16384*512
    unsigned short* vT     = kb + (size_t)NKV * 512;            // 128*64 x 1024
    unsigned short* aobH   = vT + (size_t)NKV * 512;            // 8192*512
    unsigned short* aobL   = aobH + (size_t)NQ * 512;           // 8192*512
    float2* fqt            = (float2*)(aobL + (size_t)NQ * 512); // 8192*64 f2 ++ 16384*64 f2

    prep_kernel<<<16384, 256, 0, stream>>>(
        fq, fkv, fqt,
        x_query, x_context, ln_q_g, ln_q_b, ln_c_g, ln_c_b, xq,
        Wq, WqT, Wkv, WkvT, Wout, WoutTh, WoutTl);

    mmqkv_kernel<<<1280, 256, 0, stream>>>(
        xq, xc, WqT, WkvT, qb, kb, vT, fqt, fqt + (size_t)NQ * DH);

    attn_kernel<<<512, 256, 0, stream>>>(kb, qb, vT, fqt, aobH, aobL);

    mm2_kernel<<<256, 256, 0, stream>>>(
        aobH, aobL, WoutTh, WoutTl, out, bout);
}

// Round 21
// 131.695 us; speedup vs baseline: 1.0471x; 1.0471x over previous
//
#include <hip/hip_runtime.h>

#define DIMK 512
#define NHEADS 8
#define DH 64
#define NBATCH 16
#define QLEN 512
#define KVLEN 1024
#define NQ (NBATCH*QLEN)     /* 8192  */
#define NKV (NBATCH*KVLEN)   /* 16384 */

typedef __attribute__((ext_vector_type(8))) short bf16x8;
typedef __attribute__((ext_vector_type(4))) float f32x4;
typedef __attribute__((ext_vector_type(8))) unsigned short us8;

#define QSCL 0.1803368801111204f   /* 0.125 * log2(e) : folded into q */

__device__ __forceinline__ float bf2f(unsigned short u) {
    return __uint_as_float(((unsigned)u) << 16);
}
__device__ __forceinline__ unsigned short f2bf(float f) {
    unsigned u = __float_as_uint(f);
    return (unsigned short)((u + 0x7fffu + ((u >> 16) & 1u)) >> 16);
}
__device__ __forceinline__ unsigned cvtpk(float a, float b) {
    unsigned r;
    asm("v_cvt_pk_bf16_f32 %0, %1, %2" : "=v"(r) : "v"(a), "v"(b));
    return r;
}
__device__ __forceinline__ void gl2lds16(const void* g, const void* lds) {
    __builtin_amdgcn_global_load_lds(
        (const __attribute__((address_space(1))) unsigned int*)g,
        (__attribute__((address_space(3))) unsigned int*)lds, 16, 0, 0);
}

// ---------------------------------------------------------------------------
// Fused prep (r17 verbatim): sincos tables, LN+cast, weight transposes.
// ---------------------------------------------------------------------------
__global__ __launch_bounds__(256) void prep_kernel(
    const float* __restrict__ fq, const float* __restrict__ fkv,
    float2* __restrict__ fqt,
    const float* __restrict__ xa, const float* __restrict__ xb,
    const float* __restrict__ ga, const float* __restrict__ ba,
    const float* __restrict__ gb, const float* __restrict__ bb,
    unsigned short* __restrict__ xout,
    const float* __restrict__ Wq, unsigned short* __restrict__ WqT,
    const float* __restrict__ Wkv, unsigned short* __restrict__ WkvT,
    const float* __restrict__ Wout, unsigned short* __restrict__ WoutTh,
    unsigned short* __restrict__ WoutTl)
{
    const int bid = blockIdx.x;
    const int tid = threadIdx.x;
    if (bid < 6144) {
        int i = bid * 256 + tid;
        const int na = NQ * DH;
        float f = (i < na) ? fq[i] : fkv[i - na];
        float sn, cs;
        sincosf(f, &sn, &cs);
        fqt[i] = make_float2(cs, sn);
    } else if (bid < 12288) {
        int row  = (bid - 6144) * 4 + (tid >> 6);
        int lane = tid & 63;
        bool isa = row < NQ;
        const float* x  = isa ? xa + (size_t)row * DIMK : xb + (size_t)(row - NQ) * DIMK;
        const float* g  = isa ? ga : gb;
        const float* bt = isa ? ba : bb;
        const float4* xr = reinterpret_cast<const float4*>(x);
        float4 v0 = xr[lane * 2];
        float4 v1 = xr[lane * 2 + 1];
        float s  = v0.x + v0.y + v0.z + v0.w + v1.x + v1.y + v1.z + v1.w;
        float sq = v0.x*v0.x + v0.y*v0.y + v0.z*v0.z + v0.w*v0.w
                 + v1.x*v1.x + v1.y*v1.y + v1.z*v1.z + v1.w*v1.w;
        #pragma unroll
        for (int off = 32; off; off >>= 1) {
            s  += __shfl_xor(s, off);
            sq += __shfl_xor(sq, off);
        }
        float mu   = s * (1.0f / DIMK);
        float rstd = rsqrtf(sq * (1.0f / DIMK) - mu * mu + 1e-5f);
        const float4* g4 = reinterpret_cast<const float4*>(g + lane * 8);
        const float4* b4 = reinterpret_cast<const float4*>(bt + lane * 8);
        float4 g0 = g4[0], g1 = g4[1], b0 = b4[0], b1 = b4[1];
        us8 o;
        o[0] = f2bf((v0.x - mu) * rstd * g0.x + b0.x);
        o[1] = f2bf((v0.y - mu) * rstd * g0.y + b0.y);
        o[2] = f2bf((v0.z - mu) * rstd * g0.z + b0.z);
        o[3] = f2bf((v0.w - mu) * rstd * g0.w + b0.w);
        o[4] = f2bf((v1.x - mu) * rstd * g1.x + b1.x);
        o[5] = f2bf((v1.y - mu) * rstd * g1.y + b1.y);
        o[6] = f2bf((v1.z - mu) * rstd * g1.z + b1.z);
        o[7] = f2bf((v1.w - mu) * rstd * g1.w + b1.w);
        *reinterpret_cast<us8*>(xout + (size_t)row * DIMK + lane * 8) = o;
    } else if (bid < 13312) {
        int idx = (bid - 12288) * 256 + tid;
        int n = idx >> 9, k = idx & 511;
        WqT[idx] = f2bf(Wq[(size_t)k * 512 + n]);
    } else if (bid < 15360) {
        int idx = (bid - 13312) * 256 + tid;
        int n = idx >> 9, k = idx & 511;
        WkvT[idx] = f2bf(Wkv[(size_t)k * 1024 + n]);
    } else {
        int idx = (bid - 15360) * 256 + tid;
        int n = idx >> 9, k = idx & 511;
        float v = Wout[(size_t)k * 512 + n];
        unsigned short h = f2bf(v);
        WoutTh[idx] = h;
        WoutTl[idx] = f2bf(v - bf2f(h));
    }
}

// ---------------------------------------------------------------------------
// Fused q+kv projection GEMM (r15/r19 verbatim — best known, ~58 us):
// grid 1280; tiles 0..255 = q-proj (xq @ WqT, *QSCL), 256..1279 = kv-proj
// (k compact / v transposed to vT). 128x128 tile, BK=32, 4 waves, 2-phase
// pipeline, XCD-swizzled.
// ---------------------------------------------------------------------------
__global__ __launch_bounds__(256, 2) void mmqkv_kernel(
    const unsigned short* __restrict__ xq, const unsigned short* __restrict__ xc,
    const unsigned short* __restrict__ WqT, const unsigned short* __restrict__ WkvT,
    unsigned short* __restrict__ qbout, unsigned short* __restrict__ kbout,
    unsigned short* __restrict__ vTout,
    const float2* __restrict__ fqt, const float2* __restrict__ fkvt)
{
    __shared__ __align__(16) unsigned short AsH[2][128 * 32];
    __shared__ __align__(16) unsigned short BsH[2][128 * 32];

    const int t = threadIdx.x;
    const int lane = t & 63, w = t >> 6;
    const int l15 = lane & 15, l4 = lane >> 4;
    const int wr = w >> 1, wc = w & 1;

    const int nwg  = gridDim.x;                 // 1280
    const int tile = (blockIdx.x & 7) * (nwg >> 3) + (blockIdx.x >> 3);
    const bool isq = tile < 256;
    const int tl   = isq ? tile : tile - 256;
    const int NCT  = isq ? 4 : 8;
    const unsigned short* A = isq ? xq : xc;
    const unsigned short* B = isq ? WqT : WkvT;
    const float2* fct = isq ? fqt : fkvt;
    const int row0 = (tl / NCT) * 128;
    const int col0 = (tl % NCT) * 128;

    const int stRow = lane >> 2;
    const int stK   = (lane & 3) * 8;

    auto stage = [&](int buf, int k0) {
        #pragma unroll
        for (int j = 0; j < 4; ++j) {
            int id  = w * 4 + j;
            int mat = id >> 3;
            int sub = id & 7;
            int row = sub * 16 + stRow;
            const unsigned short* gsrc = (mat == 0)
                ? A + (size_t)(row0 + row) * 512
                : B + (size_t)(col0 + row) * 512;
            unsigned short* ldst = (mat == 0) ? &AsH[buf][0] : &BsH[buf][0];
            gl2lds16(gsrc + k0 + stK, ldst + sub * 512);
        }
    };

    f32x4 acc[4][4];
    #pragma unroll
    for (int m = 0; m < 4; ++m)
        #pragma unroll
        for (int n = 0; n < 4; ++n)
            acc[m][n] = (f32x4){0.f, 0.f, 0.f, 0.f};

    stage(0, 0);
    __syncthreads();

    for (int ks = 0; ks < 16; ++ks) {
        const int cur = ks & 1;
        if (ks < 15) stage(cur ^ 1, (ks + 1) * 32);

        bf16x8 fah[4], fbh[4];
        #pragma unroll
        for (int m = 0; m < 4; ++m)
            fah[m] = *reinterpret_cast<const bf16x8*>(&AsH[cur][(wr*64 + m*16 + l15) * 32 + l4*8]);
        #pragma unroll
        for (int n = 0; n < 4; ++n)
            fbh[n] = *reinterpret_cast<const bf16x8*>(&BsH[cur][(wc*64 + n*16 + l15) * 32 + l4*8]);
        #pragma unroll
        for (int m = 0; m < 4; ++m)
            #pragma unroll
            for (int n = 0; n < 4; ++n)
                acc[m][n] = __builtin_amdgcn_mfma_f32_16x16x32_bf16(fah[m], fbh[n], acc[m][n], 0, 0, 0);
        __syncthreads();
    }

    unsigned short* pool = (w < 2) ? &AsH[w][0] : &BsH[w - 2][0];
    if (!isq && col0 >= 512) {
        const int vb    = row0 >> 10;
        const int kbase = (row0 & 1023) + wr * 64;
        const int vh    = ((col0 - 512) >> 6) + wc;
        #pragma unroll
        for (int m = 0; m < 4; ++m)
            #pragma unroll
            for (int n = 0; n < 4; ++n)
                #pragma unroll
                for (int j = 0; j < 4; ++j) {
                    float v = acc[m][n][j];
                    int gr = row0 + wr*64 + m*16 + l4*4 + j;
                    int d  = n*16 + l15;
                    float pv = __shfl_xor(v, 1);
                    float2 cn = fct[(size_t)gr * DH + d];
                    float nv = (lane & 1) ? fmaf(pv, cn.y, v * cn.x)
                                          : fmaf(-pv, cn.y, v * cn.x);
                    int kloc = m*16 + l4*4 + j;
                    int ch   = (kloc >> 3) ^ (d & 7);
                    pool[d*64 + ch*8 + (kloc & 7)] = f2bf(nv);
                }
        #pragma unroll
        for (int i = 0; i < 8; ++i) {
            int c   = i * 64 + lane;
            int dd  = c >> 3, chq = c & 7;
            int sw  = chq ^ (dd & 7);
            us8 vv = *reinterpret_cast<const us8*>(&pool[dd*64 + sw*8]);
            *reinterpret_cast<us8*>(
                &vTout[(size_t)((vb * 8 + vh) * 64 + dd) * 1024 + kbase + chq * 8]) = vv;
        }
    } else {
        unsigned short* Cout = isq ? qbout : kbout;
        #pragma unroll
        for (int m = 0; m < 4; ++m)
            #pragma unroll
            for (int n = 0; n < 4; ++n)
                #pragma unroll
                for (int j = 0; j < 4; ++j) {
                    float v = acc[m][n][j];
                    int gr = row0 + wr*64 + m*16 + l4*4 + j;
                    int d  = n*16 + l15;
                    float pv = __shfl_xor(v, 1);
                    float2 cn = fct[(size_t)gr * DH + d];
                    float nv = (lane & 1) ? fmaf(pv, cn.y, v * cn.x)
                                          : fmaf(-pv, cn.y, v * cn.x);
                    if (isq) nv *= QSCL;
                    int row = m*16 + l4*4 + j;
                    int col = n*16 + l15;
                    int ch  = (col >> 3) ^ (row & 7);
                    pool[row*64 + ch*8 + (col & 7)] = f2bf(nv);
                }
        #pragma unroll
        for (int i = 0; i < 8; ++i) {
            int c  = i * 64 + lane;
            int rl = c >> 3, ch = c & 7;
            int sw = ch ^ (rl & 7);
            us8 vv = *reinterpret_cast<const us8*>(&pool[rl*64 + sw*8]);
            int gr = row0 + wr*64 + rl;
            int gc = col0 + wc*64 + ch*8;
            *reinterpret_cast<us8*>(&Cout[(size_t)gr * 512 + gc]) = vv;
        }
    }
}

// ---------------------------------------------------------------------------
// Output GEMM (split bf16, 3 MFMA) — r17 verbatim.
// ---------------------------------------------------------------------------
__global__ __launch_bounds__(256, 2) void mm2_kernel(
    const unsigned short* __restrict__ Ah, const unsigned short* __restrict__ Al,
    const unsigned short* __restrict__ Bh, const unsigned short* __restrict__ Bl,
    float* __restrict__ Cout, const float* __restrict__ bias)
{
    __shared__ __align__(16) unsigned short AsH[2][128 * 32];
    __shared__ __align__(16) unsigned short BsH[2][128 * 32];
    __shared__ __align__(16) unsigned short AsL[2][128 * 32];
    __shared__ __align__(16) unsigned short BsL[2][128 * 32];

    const int t = threadIdx.x;
    const int lane = t & 63, w = t >> 6;
    const int l15 = lane & 15, l4 = lane >> 4;
    const int wr = w >> 1, wc = w & 1;

    const int nwg  = gridDim.x;
    const int tile = (blockIdx.x & 7) * (nwg >> 3) + (blockIdx.x >> 3);
    const int row0 = (tile >> 2) * 128;
    const int col0 = (tile & 3) * 128;

    const int stRow = lane >> 2;
    const int stK   = (lane & 3) * 8;

    auto stage = [&](int buf, int k0) {
        #pragma unroll
        for (int j = 0; j < 8; ++j) {
            int id  = w * 8 + j;
            int mat = id >> 3;
            int sub = id & 7;
            int row = sub * 16 + stRow;
            const unsigned short* gsrc =
                (mat == 0) ? Ah + (size_t)(row0 + row) * 512 :
                (mat == 1) ? Bh + (size_t)(col0 + row) * 512 :
                (mat == 2) ? Al + (size_t)(row0 + row) * 512 :
                             Bl + (size_t)(col0 + row) * 512;
            unsigned short* ldst =
                (mat == 0) ? &AsH[buf][0] :
                (mat == 1) ? &BsH[buf][0] :
                (mat == 2) ? &AsL[buf][0] :
                             &BsL[buf][0];
            gl2lds16(gsrc + k0 + stK, ldst + sub * 512);
        }
    };

    f32x4 acc[4][4];
    #pragma unroll
    for (int m = 0; m < 4; ++m)
        #pragma unroll
        for (int n = 0; n < 4; ++n)
            acc[m][n] = (f32x4){0.f, 0.f, 0.f, 0.f};

    stage(0, 0);
    __syncthreads();

    for (int ks = 0; ks < 16; ++ks) {
        const int cur = ks & 1;
        if (ks < 15) stage(cur ^ 1, (ks + 1) * 32);

        bf16x8 fah[4], fbh[4], fal[4], fbl[4];
        #pragma unroll
        for (int m = 0; m < 4; ++m) {
            fah[m] = *reinterpret_cast<const bf16x8*>(&AsH[cur][(wr*64 + m*16 + l15) * 32 + l4*8]);
            fal[m] = *reinterpret_cast<const bf16x8*>(&AsL[cur][(wr*64 + m*16 + l15) * 32 + l4*8]);
        }
        #pragma unroll
        for (int n = 0; n < 4; ++n) {
            fbh[n] = *reinterpret_cast<const bf16x8*>(&BsH[cur][(wc*64 + n*16 + l15) * 32 + l4*8]);
            fbl[n] = *reinterpret_cast<const bf16x8*>(&BsL[cur][(wc*64 + n*16 + l15) * 32 + l4*8]);
        }
        #pragma unroll
        for (int m = 0; m < 4; ++m)
            #pragma unroll
            for (int n = 0; n < 4; ++n) {
                acc[m][n] = __builtin_amdgcn_mfma_f32_16x16x32_bf16(fah[m], fbh[n], acc[m][n], 0, 0, 0);
                acc[m][n] = __builtin_amdgcn_mfma_f32_16x16x32_bf16(fah[m], fbl[n], acc[m][n], 0, 0, 0);
                acc[m][n] = __builtin_amdgcn_mfma_f32_16x16x32_bf16(fal[m], fbh[n], acc[m][n], 0, 0, 0);
            }
        __syncthreads();
    }

    #pragma unroll
    for (int m = 0; m < 4; ++m)
        #pragma unroll
        for (int n = 0; n < 4; ++n)
            #pragma unroll
            for (int j = 0; j < 4; ++j) {
                int gr = row0 + wr*64 + m*16 + l4*4 + j;
                int gc = col0 + wc*64 + n*16 + l15;
                Cout[(size_t)gr * 512 + gc] = acc[m][n][j] + bias[gc];
            }
}

// ---------------------------------------------------------------------------
// MFMA flash attention — r17 verbatim (passing): r12 sync structure +
// q-multi x2, disjoint P regions, no setprio.
// ---------------------------------------------------------------------------
__global__ __launch_bounds__(256, 2) void attn_kernel(
    const unsigned short* __restrict__ kb, const unsigned short* __restrict__ qb,
    const unsigned short* __restrict__ vT, const float2* __restrict__ fqt,
    unsigned short* __restrict__ aobH, unsigned short* __restrict__ aobL)
{
    __shared__ __align__(16) unsigned short Vs[4][4096];   // 4-buffer V ring
    __shared__ __align__(16) unsigned short Ps[4][2048];   // [wave][set*1024+idx]

    const int bid  = blockIdx.x;
    const int tile = (bid & 7) * 64 + (bid >> 3);   // nwg=512, bijective
    const int qs = tile & 3, h = (tile >> 2) & 7, b = tile >> 5;
    const int t = threadIdx.x, lane = t & 63, w = t >> 6;
    const int l15 = lane & 15, l4 = lane >> 4;
    const int bh = b * 8 + h;

    const int q_row0 = b * QLEN + qs * 128 + w * 16;   // set0; set1 = +64
    const size_t kvr0 = (size_t)b * KVLEN;

    constexpr float RTHR = 11.5415585f;   // 8 * log2e (exp2 domain)

    bf16x8 qf0 = *reinterpret_cast<const bf16x8*>(
        &qb[(size_t)(q_row0 + l15) * 512 + h * 64 + l4 * 8]);
    bf16x8 qf1 = *reinterpret_cast<const bf16x8*>(
        &qb[(size_t)(q_row0 + l15) * 512 + h * 64 + 32 + l4 * 8]);
    bf16x8 qg0 = *reinterpret_cast<const bf16x8*>(
        &qb[(size_t)(q_row0 + 64 + l15) * 512 + h * 64 + l4 * 8]);
    bf16x8 qg1 = *reinterpret_cast<const bf16x8*>(
        &qb[(size_t)(q_row0 + 64 + l15) * 512 + h * 64 + 32 + l4 * 8]);

    auto stageVT = [&](int buf, int kt) {
        #pragma unroll
        for (int i = 0; i < 2; ++i) {
            const int dbase = (w * 2 + i) * 8;
            const int dlo = lane >> 3;
            const int cb  = lane & 7;
            gl2lds16(&vT[(size_t)(bh * 64 + dbase + dlo) * 1024 + kt * 64
                         + ((cb ^ dlo) * 8)],
                     &Vs[buf][dbase * 64]);
        }
    };

    auto loadK = [&](bf16x8 (&dst)[4][2], int kt) {
        #pragma unroll
        for (int n = 0; n < 4; ++n) {
            const unsigned short* krow =
                &kb[(kvr0 + kt * 64 + n * 16 + l15) * 512 + h * 64];
            dst[n][0] = *reinterpret_cast<const bf16x8*>(&krow[l4 * 8]);
            dst[n][1] = *reinterpret_cast<const bf16x8*>(&krow[32 + l4 * 8]);
        }
    };

    f32x4 o0[4], o1[4];
    #pragma unroll
    for (int dt = 0; dt < 4; ++dt) {
        o0[dt] = (f32x4){0.f, 0.f, 0.f, 0.f};
        o1[dt] = (f32x4){0.f, 0.f, 0.f, 0.f};
    }
    float m0 = -3.0e38f, l0 = 0.f, m1 = -3.0e38f, l1 = 0.f;

    unsigned short* pw0 = &Ps[w][0];
    unsigned short* pw1 = &Ps[w][1024];

    auto iter = [&](int vbuf, bf16x8 (&KC)[4][2]) {
        // ================= set 0 =================
        {
            f32x4 s[4];
            #pragma unroll
            for (int n = 0; n < 4; ++n) {
                f32x4 a = (f32x4){0.f, 0.f, 0.f, 0.f};
                a = __builtin_amdgcn_mfma_f32_16x16x32_bf16(KC[n][0], qf0, a, 0, 0, 0);
                a = __builtin_amdgcn_mfma_f32_16x16x32_bf16(KC[n][1], qf1, a, 0, 0, 0);
                s[n] = a;
            }
            float pmax = -3.0e38f;
            #pragma unroll
            for (int n = 0; n < 4; ++n)
                #pragma unroll
                for (int j = 0; j < 4; ++j)
                    pmax = fmaxf(pmax, s[n][j]);
            pmax = fmaxf(pmax, __shfl_xor(pmax, 16));
            pmax = fmaxf(pmax, __shfl_xor(pmax, 32));
            if (!__all(pmax - m0 <= RTHR)) {
                float mnew = fmaxf(m0, pmax);
                float al = __builtin_amdgcn_exp2f(m0 - mnew);
                l0 *= al;
                float a0 = __shfl(al, l4 * 4 + 0);
                float a1 = __shfl(al, l4 * 4 + 1);
                float a2 = __shfl(al, l4 * 4 + 2);
                float a3 = __shfl(al, l4 * 4 + 3);
                #pragma unroll
                for (int dt = 0; dt < 4; ++dt) {
                    o0[dt][0] *= a0; o0[dt][1] *= a1; o0[dt][2] *= a2; o0[dt][3] *= a3;
                }
                m0 = mnew;
            }
            float rs = 0.f;
            #pragma unroll
            for (int n = 0; n < 4; ++n) {
                float p0 = __builtin_amdgcn_exp2f(s[n][0] - m0);
                float p1 = __builtin_amdgcn_exp2f(s[n][1] - m0);
                float p2 = __builtin_amdgcn_exp2f(s[n][2] - m0);
                float p3 = __builtin_amdgcn_exp2f(s[n][3] - m0);
                rs += (p0 + p1) + (p2 + p3);
                uint2 pk = make_uint2(cvtpk(p0, p1), cvtpk(p2, p3));
                int idx = l15 * 64 + ((n * 16 + l4 * 4) ^ ((l15 & 7) << 3));
                *reinterpret_cast<uint2*>(&pw0[idx]) = pk;
            }
            rs += __shfl_xor(rs, 16);
            rs += __shfl_xor(rs, 32);
            l0 += rs;

            bf16x8 pfh[2];
            #pragma unroll
            for (int c = 0; c < 2; ++c) {
                int idx = l15 * 64 + ((c * 32 + l4 * 8) ^ ((l15 & 7) << 3));
                pfh[c] = *reinterpret_cast<const bf16x8*>(&pw0[idx]);
            }
            #pragma unroll
            for (int dt = 0; dt < 4; ++dt) {
                int d = dt * 16 + l15;
                #pragma unroll
                for (int c = 0; c < 2; ++c) {
                    int vidx = d * 64 + ((c * 32 + l4 * 8) ^ ((d & 7) << 3));
                    bf16x8 vf = *reinterpret_cast<const bf16x8*>(&Vs[vbuf][vidx]);
                    o0[dt] = __builtin_amdgcn_mfma_f32_16x16x32_bf16(pfh[c], vf, o0[dt], 0, 0, 0);
                }
            }
        }
        // ================= set 1 =================
        {
            f32x4 s[4];
            #pragma unroll
            for (int n = 0; n < 4; ++n) {
                f32x4 a = (f32x4){0.f, 0.f, 0.f, 0.f};
                a = __builtin_amdgcn_mfma_f32_16x16x32_bf16(KC[n][0], qg0, a, 0, 0, 0);
                a = __builtin_amdgcn_mfma_f32_16x16x32_bf16(KC[n][1], qg1, a, 0, 0, 0);
                s[n] = a;
            }
            float pmax = -3.0e38f;
            #pragma unroll
            for (int n = 0; n < 4; ++n)
                #pragma unroll
                for (int j = 0; j < 4; ++j)
                    pmax = fmaxf(pmax, s[n][j]);
            pmax = fmaxf(pmax, __shfl_xor(pmax, 16));
            pmax = fmaxf(pmax, __shfl_xor(pmax, 32));
            if (!__all(pmax - m1 <= RTHR)) {
                float mnew = fmaxf(m1, pmax);
                float al = __builtin_amdgcn_exp2f(m1 - mnew);
                l1 *= al;
                float a0 = __shfl(al, l4 * 4 + 0);
                float a1 = __shfl(al, l4 * 4 + 1);
                float a2 = __shfl(al, l4 * 4 + 2);
                float a3 = __shfl(al, l4 * 4 + 3);
                #pragma unroll
                for (int dt = 0; dt < 4; ++dt) {
                    o1[dt][0] *= a0; o1[dt][1] *= a1; o1[dt][2] *= a2; o1[dt][3] *= a3;
                }
                m1 = mnew;
            }
            float rs = 0.f;
            #pragma unroll
            for (int n = 0; n < 4; ++n) {
                float p0 = __builtin_amdgcn_exp2f(s[n][0] - m1);
                float p1 = __builtin_amdgcn_exp2f(s[n][1] - m1);
                float p2 = __builtin_amdgcn_exp2f(s[n][2] - m1);
                float p3 = __builtin_amdgcn_exp2f(s[n][3] - m1);
                rs += (p0 + p1) + (p2 + p3);
                uint2 pk = make_uint2(cvtpk(p0, p1), cvtpk(p2, p3));
                int idx = l15 * 64 + ((n * 16 + l4 * 4) ^ ((l15 & 7) << 3));
                *reinterpret_cast<uint2*>(&pw1[idx]) = pk;
            }
            rs += __shfl_xor(rs, 16);
            rs += __shfl_xor(rs, 32);
            l1 += rs;

            bf16x8 pfh[2];
            #pragma unroll
            for (int c = 0; c < 2; ++c) {
                int idx = l15 * 64 + ((c * 32 + l4 * 8) ^ ((l15 & 7) << 3));
                pfh[c] = *reinterpret_cast<const bf16x8*>(&pw1[idx]);
            }
            #pragma unroll
            for (int dt = 0; dt < 4; ++dt) {
                int d = dt * 16 + l15;
                #pragma unroll
                for (int c = 0; c < 2; ++c) {
                    int vidx = d * 64 + ((c * 32 + l4 * 8) ^ ((d & 7) << 3));
                    bf16x8 vf = *reinterpret_cast<const bf16x8*>(&Vs[vbuf][vidx]);
                    o1[dt] = __builtin_amdgcn_mfma_f32_16x16x32_bf16(pfh[c], vf, o1[dt], 0, 0, 0);
                }
            }
        }
    };

    bf16x8 kA[4][2], kB[4][2];
    stageVT(0, 0);
    stageVT(1, 1);
    loadK(kA, 0);

    for (int kt = 0; kt < 16; kt += 2) {
        __syncthreads();
        if (kt < 14) {
            stageVT((kt + 2) & 3, kt + 2);
            stageVT((kt + 3) & 3, kt + 3);
        }
        loadK(kB, kt + 1);
        iter(kt & 3, kA);
        if (kt < 14) loadK(kA, kt + 2);
        iter((kt + 1) & 3, kB);
    }

    __syncthreads();
    unsigned short* pe = &Vs[w][0];

    {   // ---- set 0 ----
        unsigned short* ps = pe;
        float linv = 1.f / l0;
        #pragma unroll
        for (int r = 0; r < 4; ++r) {
            float lr = __shfl(linv, l4 * 4 + r);
            int gr = q_row0 + l4 * 4 + r;
            #pragma unroll
            for (int dt = 0; dt < 4; ++dt) {
                int d = dt * 16 + l15;
                float val = o0[dt][r] * lr;
                float pv = __shfl_xor(val, 1);
                float2 cn = fqt[(size_t)gr * DH + d];
                float rr = (d & 1) ? (val * cn.x - pv * cn.y) : (val * cn.x + pv * cn.y);
                unsigned short hi = f2bf(rr);
                float lo = rr - bf2f(hi);
                int row = l4 * 4 + r;
                int ch  = (d >> 3) ^ (row & 7);
                ps[row*64 + ch*8 + (d & 7)] = hi;
                ps[1024 + row*64 + ch*8 + (d & 7)] = f2bf(lo);
            }
        }
        #pragma unroll
        for (int i = 0; i < 2; ++i) {
            int c  = i * 64 + lane;
            int rl = c >> 3, ch = c & 7;
            int sw = ch ^ (rl & 7);
            us8 vh = *reinterpret_cast<const us8*>(&ps[rl*64 + sw*8]);
            us8 vl = *reinterpret_cast<const us8*>(&ps[1024 + rl*64 + sw*8]);
            size_t off = (size_t)(q_row0 + rl) * 512 + h * 64 + ch * 8;
            *reinterpret_cast<us8*>(&aobH[off]) = vh;
            *reinterpret_cast<us8*>(&aobL[off]) = vl;
        }
    }
    {   // ---- set 1 ----
        unsigned short* ps = pe + 2048;
        float linv = 1.f / l1;
        #pragma unroll
        for (int r = 0; r < 4; ++r) {
            float lr = __shfl(linv, l4 * 4 + r);
            int gr = q_row0 + 64 + l4 * 4 + r;
            #pragma unroll
            for (int dt = 0; dt < 4; ++dt) {
                int d = dt * 16 + l15;
                float val = o1[dt][r] * lr;
                float pv = __shfl_xor(val, 1);
                float2 cn = fqt[(size_t)gr * DH + d];
                float rr = (d & 1) ? (val * cn.x - pv * cn.y) : (val * cn.x + pv * cn.y);
                unsigned short hi = f2bf(rr);
                float lo = rr - bf2f(hi);
                int row = l4 * 4 + r;
                int ch  = (d >> 3) ^ (row & 7);
                ps[row*64 + ch*8 + (d & 7)] = hi;
                ps[1024 + row*64 + ch*8 + (d & 7)] = f2bf(lo);
            }
        }
        #pragma unroll
        for (int i = 0; i < 2; ++i) {
            int c  = i * 64 + lane;
            int rl = c >> 3, ch = c & 7;
            int sw = ch ^ (rl & 7);
            us8 vh = *reinterpret_cast<const us8*>(&ps[rl*64 + sw*8]);
            us8 vl = *reinterpret_cast<const us8*>(&ps[1024 + rl*64 + sw*8]);
            size_t off = (size_t)(q_row0 + 64 + rl) * 512 + h * 64 + ch * 8;
            *reinterpret_cast<us8*>(&aobH[off]) = vh;
            *reinterpret_cast<us8*>(&aobL[off]) = vl;
        }
    }
}

// ---------------------------------------------------------------------------
extern "C" void kernel_launch(void* const* d_in, const int* in_sizes, int n_in,
                              void* d_out, int out_size, void* d_ws, size_t ws_size,
                              hipStream_t stream) {
    const float* x_query   = (const float*)d_in[0];
    const float* x_context = (const float*)d_in[1];
    const float* fq        = (const float*)d_in[2];
    const float* fkv       = (const float*)d_in[3];
    const float* ln_q_g    = (const float*)d_in[4];
    const float* ln_q_b    = (const float*)d_in[5];
    const float* ln_c_g    = (const float*)d_in[6];
    const float* ln_c_b    = (const float*)d_in[7];
    const float* Wq        = (const float*)d_in[8];
    const float* Wkv       = (const float*)d_in[9];
    const float* Wout      = (const float*)d_in[10];
    const float* bout      = (const float*)d_in[11];
    float* out = (float*)d_out;

    unsigned short* xq     = (unsigned short*)d_ws;             // 8192*512
    unsigned short* xc     = xq + (size_t)NQ * 512;             // 16384*512
    unsigned short* WqT    = xc + (size_t)NKV * 512;            // 512*512
    unsigned short* WkvT   = WqT + 512 * 512;                   // 1024*512
    unsigned short* WoutTh = WkvT + 1024 * 512;                 // 512*512
    unsigned short* WoutTl = WoutTh + 512 * 512;                // 512*512
    unsigned short* qb     = WoutTl + 512 * 512;                // 8192*512
    unsigned short* kb     = qb + (size_t)NQ * 512;             // 16384*512
    unsigned short* vT     = kb + (size_t)NKV * 512;            // 128*64 x 1024
    unsigned short* aobH   = vT + (size_t)NKV * 512;            // 8192*512
    unsigned short* aobL   = aobH + (size_t)NQ * 512;           // 8192*512
    float2* fqt            = (float2*)(aobL + (size_t)NQ * 512); // 8192*64 f2 ++ 16384*64 f2

    prep_kernel<<<16384, 256, 0, stream>>>(
        fq, fkv, fqt,
        x_query, x_context, ln_q_g, ln_q_b, ln_c_g, ln_c_b, xq,
        Wq, WqT, Wkv, WkvT, Wout, WoutTh, WoutTl);

    mmqkv_kernel<<<1280, 256, 0, stream>>>(
        xq, xc, WqT, WkvT, qb, kb, vT, fqt, fqt + (size_t)NQ * DH);

    attn_kernel<<<512, 256, 0, stream>>>(kb, qb, vT, fqt, aobH, aobL);

    mm2_kernel<<<256, 256, 0, stream>>>(
        aobH, aobL, WoutTh, WoutTl, out, bout);
}